// Round 1
// baseline (545.954 us; speedup 1.0000x reference)
//
#include <hip/hip_runtime.h>

// Problem constants: B=4, S=256, E=640, H=256, L=3, N2=H/2=128
// h rows are flattened [B*S, H] = [1024, 256].

// ---------------------------------------------------------------------------
// Generic fp32 tiled GEMM:  C[m,n] = (relu?)(sum_k A[m,k]*B[k,n] + bias[n])
// Tiles: BM=BN=64, BK=32. 256 threads, 4x4 microtile per thread.
// Requires M%64==0, N%64==0, K%32==0 (true for all uses here).
// Batched via blockIdx.z with element strides aB/bB/cB.
// ---------------------------------------------------------------------------
template<bool RELU>
__global__ __launch_bounds__(256)
void gemm_nn(const float* __restrict__ A, const float* __restrict__ B,
             const float* __restrict__ bias, float* __restrict__ C,
             int M, int N, int K, int aB, int bB, int cB)
{
    A += (long)blockIdx.z * aB;
    B += (long)blockIdx.z * bB;
    C += (long)blockIdx.z * cB;
    const int m0 = blockIdx.y * 64, n0 = blockIdx.x * 64;
    __shared__ float As[32][68];   // transposed A tile: As[k][m]
    __shared__ float Bs[32][68];   // Bs[k][n]
    const int tid = threadIdx.x;
    const int tx = tid & 15, ty = tid >> 4;
    float acc[4][4] = {};

    for (int k0 = 0; k0 < K; k0 += 32) {
        // A tile: 64 rows x 32 k = 512 float4, 2 per thread
#pragma unroll
        for (int q = 0; q < 2; ++q) {
            int f = tid * 2 + q;               // 0..511
            int row = f >> 3, kk = (f & 7) << 2;
            float4 v = *(const float4*)&A[(long)(m0 + row) * K + k0 + kk];
            As[kk + 0][row] = v.x; As[kk + 1][row] = v.y;
            As[kk + 2][row] = v.z; As[kk + 3][row] = v.w;
        }
        // B tile: 32 k x 64 n = 512 float4, 2 per thread
#pragma unroll
        for (int q = 0; q < 2; ++q) {
            int f = tid * 2 + q;
            int kk = f >> 4, nn = (f & 15) << 2;
            *(float4*)&Bs[kk][nn] = *(const float4*)&B[(long)(k0 + kk) * N + n0 + nn];
        }
        __syncthreads();
#pragma unroll
        for (int k = 0; k < 32; ++k) {
            float4 a = *(const float4*)&As[k][ty << 2];
            float4 b = *(const float4*)&Bs[k][tx << 2];
            float av[4] = {a.x, a.y, a.z, a.w};
            float bv[4] = {b.x, b.y, b.z, b.w};
#pragma unroll
            for (int i = 0; i < 4; ++i)
#pragma unroll
                for (int j = 0; j < 4; ++j)
                    acc[i][j] += av[i] * bv[j];
        }
        __syncthreads();
    }

#pragma unroll
    for (int i = 0; i < 4; ++i) {
        int m = m0 + (ty << 2) + i;
#pragma unroll
        for (int j = 0; j < 4; ++j) {
            int n = n0 + (tx << 2) + j;
            float v = acc[i][j];
            if (bias) v += bias[n];
            if (RELU) v = fmaxf(v, 0.f);
            C[(long)m * N + n] = v;
        }
    }
}

// ---------------------------------------------------------------------------
// h = LayerNorm(relu(self_f + neigh)) * g + b   — one block per row of 256
// ---------------------------------------------------------------------------
__global__ __launch_bounds__(256)
void add_relu_ln(const float* __restrict__ a, const float* __restrict__ b,
                 const float* __restrict__ g, const float* __restrict__ bb,
                 float* __restrict__ o)
{
    const int row = blockIdx.x, t = threadIdx.x;
    const long idx = (long)row * 256 + t;
    float x = fmaxf(a[idx] + b[idx], 0.f);
    float s = x, s2 = x * x;
#pragma unroll
    for (int off = 1; off < 64; off <<= 1) {
        s  += __shfl_xor(s,  off, 64);
        s2 += __shfl_xor(s2, off, 64);
    }
    __shared__ float ws1[4], ws2[4];
    const int wid = t >> 6, lane = t & 63;
    if (lane == 0) { ws1[wid] = s; ws2[wid] = s2; }
    __syncthreads();
    s  = ws1[0] + ws1[1] + ws1[2] + ws1[3];
    s2 = ws2[0] + ws2[1] + ws2[2] + ws2[3];
    const float mu  = s * (1.f / 256.f);
    const float var = s2 * (1.f / 256.f) - mu * mu;
    o[idx] = (x - mu) * rsqrtf(var + 1e-5f) * g[t] + bb[t];
}

// ---------------------------------------------------------------------------
// Fused pairwise scorer.
// Per block: 16 i x 8 j = 128 pairs for one batch b.
//   P[pair,k] = relu(hi[i,k] + hj[j,k] + bp[i,j]*c[k] + b1[k])   (built in LDS)
//   Q[pair,n] = relu(sum_k P*W2[k,n] + b2[n])                    (reg microtile)
//   out[b,i,j] = sum_n Q*w3[n] + b3                              (LDS reduce)
// K = 256 channels, 8 tiles of 32.  N = 128.
// ---------------------------------------------------------------------------
__global__ __launch_bounds__(256)
void pairwise(const float* __restrict__ hi, const float* __restrict__ hj,
              const float* __restrict__ bp,
              const float* __restrict__ c,    // mlp_w1 row 512   [256]
              const float* __restrict__ b1,   // [256]
              const float* __restrict__ w2,   // [256][128]
              const float* __restrict__ b2,   // [128]
              const float* __restrict__ w3,   // [128]
              const float* __restrict__ b3,   // [1]
              float* __restrict__ out)
{
    const int b = blockIdx.z, i0 = blockIdx.y * 16, j0 = blockIdx.x * 8;
    const int tid = threadIdx.x;

    __shared__ float Ps[32][132];
    __shared__ float W2s[32][132];
    __shared__ float his[16][36];
    __shared__ float hjs[8][36];
    __shared__ float cs[32], b1s[32];
    __shared__ float bpv[128];
    __shared__ float b2s[128], w3s[128];
    __shared__ float red[128][18];

    if (tid < 128) {
        bpv[tid] = bp[((long)(b * 256 + i0 + (tid >> 3))) * 256 + j0 + (tid & 7)];
        b2s[tid] = b2[tid];
        w3s[tid] = w3[tid];
    }

    const int tp = tid & 15, tn = tid >> 4;   // pairs tp*8..+7, n tn*8..+7
    float acc[8][8] = {};

    for (int k0 = 0; k0 < 256; k0 += 32) {
        // ---- stage hi/hj/c/b1 slices ----
        if (tid < 128) {
            int r = tid >> 3, k4 = (tid & 7) << 2;
            *(float4*)&his[r][k4] =
                *(const float4*)&hi[((long)(b * 256 + i0 + r)) * 256 + k0 + k4];
        } else if (tid < 192) {
            int t2 = tid - 128;
            int r = t2 >> 3, k4 = (t2 & 7) << 2;
            *(float4*)&hjs[r][k4] =
                *(const float4*)&hj[((long)(b * 256 + j0 + r)) * 256 + k0 + k4];
        } else if (tid < 224) {
            int kk = tid - 192;
            cs[kk]  = c[k0 + kk];
            b1s[kk] = b1[k0 + kk];
        }
        // ---- stage W2 tile: 32x128 = 1024 float4, 4 per thread ----
#pragma unroll
        for (int q = 0; q < 4; ++q) {
            int f = tid * 4 + q;               // 0..1023
            int kk = f >> 5, n4 = (f & 31) << 2;
            *(float4*)&W2s[kk][n4] = *(const float4*)&w2[(long)(k0 + kk) * 128 + n4];
        }
        __syncthreads();

        // ---- build P tile (transposed: Ps[k][pair]) ----
        {
            int p = tid & 127, half = tid >> 7;
            int ii = p >> 3, jj = p & 7;
            float w = bpv[p];
#pragma unroll
            for (int q = 0; q < 16; ++q) {
                int k = half * 16 + q;
                Ps[k][p] = fmaxf(his[ii][k] + hjs[jj][k] + w * cs[k] + b1s[k], 0.f);
            }
        }
        __syncthreads();

        // ---- MAC: 8 pairs x 8 n per thread ----
#pragma unroll
        for (int k = 0; k < 32; ++k) {
            float4 a0 = *(const float4*)&Ps[k][tp * 8];
            float4 a1 = *(const float4*)&Ps[k][tp * 8 + 4];
            float4 c0 = *(const float4*)&W2s[k][tn * 8];
            float4 c1 = *(const float4*)&W2s[k][tn * 8 + 4];
            float av[8] = {a0.x, a0.y, a0.z, a0.w, a1.x, a1.y, a1.z, a1.w};
            float bv[8] = {c0.x, c0.y, c0.z, c0.w, c1.x, c1.y, c1.z, c1.w};
#pragma unroll
            for (int i = 0; i < 8; ++i)
#pragma unroll
                for (int j = 0; j < 8; ++j)
                    acc[i][j] += av[i] * bv[j];
        }
        __syncthreads();
    }

    // ---- epilogue: relu(+b2), dot w3, reduce over the 16 n-groups ----
    const float b3v = b3[0];
#pragma unroll
    for (int i = 0; i < 8; ++i) {
        float sum = 0.f;
#pragma unroll
        for (int j = 0; j < 8; ++j) {
            int n = tn * 8 + j;
            float q = fmaxf(acc[i][j] + b2s[n], 0.f);
            sum += q * w3s[n];
        }
        red[tp * 8 + i][tn] = sum;
    }
    __syncthreads();
    if (tid < 128) {
        float s = 0.f;
#pragma unroll
        for (int t = 0; t < 16; ++t) s += red[tid][t];
        out[((long)(b * 256 + i0 + (tid >> 3))) * 256 + j0 + (tid & 7)] = s + b3v;
    }
}

// ---------------------------------------------------------------------------
extern "C" void kernel_launch(void* const* d_in, const int* in_sizes, int n_in,
                              void* d_out, int out_size, void* d_ws, size_t ws_size,
                              hipStream_t stream)
{
    const float* emb   = (const float*)d_in[0];   // [4,256,640]
    const float* bp    = (const float*)d_in[1];   // [4,256,256]
    // d_in[2] sequence_lengths unused (all == S)
    const float* ew1   = (const float*)d_in[3];   // [640,512]
    const float* eb1   = (const float*)d_in[4];
    const float* ew2   = (const float*)d_in[5];   // [512,256]
    const float* eb2   = (const float*)d_in[6];
    const float* wself = (const float*)d_in[7];   // [3,256,256]
    const float* bself = (const float*)d_in[8];
    const float* wedge = (const float*)d_in[9];
    const float* bedge = (const float*)d_in[10];
    const float* lng   = (const float*)d_in[11];
    const float* lnb   = (const float*)d_in[12];
    const float* mw1   = (const float*)d_in[13];  // [513,256]
    const float* mb1   = (const float*)d_in[14];
    const float* mw2   = (const float*)d_in[15];  // [256,128]
    const float* mb2   = (const float*)d_in[16];
    const float* mw3   = (const float*)d_in[17];  // [128,1]
    const float* mb3   = (const float*)d_in[18];  // [1]
    float* out = (float*)d_out;

    float* ws = (float*)d_ws;
    float* h1 = ws;              // 1024*512
    float* h  = h1 + 524288;     // 1024*256
    float* sf = h  + 262144;     // self_f
    float* eg = sf + 262144;     // edge
    float* ng = eg + 262144;     // neigh
    float* hi = ng + 262144;
    float* hj = hi + 262144;     // total 2,097,152 floats = 8 MB

    dim3 blk(256);

    // FeatureEncoder
    gemm_nn<true ><<<dim3(8, 16, 1), blk, 0, stream>>>(emb, ew1, eb1, h1, 1024, 512, 640, 0, 0, 0);
    gemm_nn<false><<<dim3(4, 16, 1), blk, 0, stream>>>(h1, ew2, eb2, h, 1024, 256, 512, 0, 0, 0);

    // GCN layers
    for (int l = 0; l < 3; ++l) {
        gemm_nn<false><<<dim3(4, 16, 1), blk, 0, stream>>>(h, wself + l * 65536, bself + l * 256, sf, 1024, 256, 256, 0, 0, 0);
        gemm_nn<false><<<dim3(4, 16, 1), blk, 0, stream>>>(h, wedge + l * 65536, bedge + l * 256, eg, 1024, 256, 256, 0, 0, 0);
        gemm_nn<false><<<dim3(4, 4, 4), blk, 0, stream>>>(bp, eg, nullptr, ng, 256, 256, 256, 65536, 65536, 65536);
        add_relu_ln<<<dim3(1024), blk, 0, stream>>>(sf, ng, lng + l * 256, lnb + l * 256, h);
    }

    // Pairwise scorer partial products
    gemm_nn<false><<<dim3(4, 16, 1), blk, 0, stream>>>(h, mw1,         nullptr, hi, 1024, 256, 256, 0, 0, 0);
    gemm_nn<false><<<dim3(4, 16, 1), blk, 0, stream>>>(h, mw1 + 65536, nullptr, hj, 1024, 256, 256, 0, 0, 0);

    // Fused pairwise MLP:  grid = (S/8 j-tiles, S/16 i-tiles, B)
    pairwise<<<dim3(32, 16, 4), blk, 0, stream>>>(hi, hj, bp,
                                                  mw1 + 131072, mb1,
                                                  mw2, mb2, mw3, mb3, out);
}

// Round 2
// 353.706 us; speedup vs baseline: 1.5435x; 1.5435x over previous
//
#include <hip/hip_runtime.h>

typedef __attribute__((ext_vector_type(8))) short short8;
typedef __attribute__((ext_vector_type(4))) float f32x4;

__device__ __forceinline__ unsigned short f2bf(float x) {
    union { float f; unsigned u; } v; v.f = x;
    unsigned r = v.u + 0x7FFF + ((v.u >> 16) & 1);
    return (unsigned short)(r >> 16);
}
__device__ __forceinline__ float bf2f(unsigned short h) {
    union { unsigned u; float f; } v; v.u = ((unsigned)h) << 16;
    return v.f;
}

// ---------------------------------------------------------------------------
// Dense fp32 GEMM, BM=32 BN=64 BK=32, 256 thr, 2x4 microtile.
// Dual-output capable (shares A): blocks with bx>=nxHalf compute B1/C1.
// Batched via blockIdx.z strides.
// ---------------------------------------------------------------------------
template<bool RELU>
__global__ __launch_bounds__(256)
void gemm32(const float* __restrict__ A, const float* __restrict__ B0,
            const float* __restrict__ bias0, float* __restrict__ C0,
            const float* __restrict__ B1, const float* __restrict__ bias1,
            float* __restrict__ C1,
            int M, int N, int K, int aB, int bB, int cB, int nxHalf)
{
    int bx = blockIdx.x;
    const float* B = B0; const float* bias = bias0; float* C = C0;
    if (nxHalf && bx >= nxHalf) { bx -= nxHalf; B = B1; bias = bias1; C = C1; }
    A += (long)blockIdx.z * aB;
    B += (long)blockIdx.z * bB;
    C += (long)blockIdx.z * cB;
    const int m0 = blockIdx.y * 32, n0 = bx * 64;

    __shared__ __align__(16) float As[32][36];   // As[k][m]
    __shared__ __align__(16) float Bs[32][68];   // Bs[k][n]
    const int tid = threadIdx.x;
    const int tx = tid & 15, ty = tid >> 4;
    float acc[2][4] = {};

    for (int k0 = 0; k0 < K; k0 += 32) {
        {
            int row = tid >> 3, kq = (tid & 7) << 2;
            float4 v = *(const float4*)&A[(long)(m0 + row) * K + k0 + kq];
            As[kq + 0][row] = v.x; As[kq + 1][row] = v.y;
            As[kq + 2][row] = v.z; As[kq + 3][row] = v.w;
        }
#pragma unroll
        for (int q = 0; q < 2; ++q) {
            int f = tid * 2 + q;
            int kk = f >> 4, nn = (f & 15) << 2;
            *(float4*)&Bs[kk][nn] = *(const float4*)&B[(long)(k0 + kk) * N + n0 + nn];
        }
        __syncthreads();
#pragma unroll
        for (int k = 0; k < 32; ++k) {
            float2 a2 = *(const float2*)&As[k][ty * 2];
            float4 b4 = *(const float4*)&Bs[k][tx * 4];
            acc[0][0] += a2.x * b4.x; acc[0][1] += a2.x * b4.y;
            acc[0][2] += a2.x * b4.z; acc[0][3] += a2.x * b4.w;
            acc[1][0] += a2.y * b4.x; acc[1][1] += a2.y * b4.y;
            acc[1][2] += a2.y * b4.z; acc[1][3] += a2.y * b4.w;
        }
        __syncthreads();
    }

#pragma unroll
    for (int i = 0; i < 2; ++i) {
        int m = m0 + ty * 2 + i;
#pragma unroll
        for (int j = 0; j < 4; ++j) {
            int n = n0 + tx * 4 + j;
            float v = acc[i][j];
            if (bias) v += bias[n];
            if (RELU) v = fmaxf(v, 0.f);
            C[(long)m * N + n] = v;
        }
    }
}

// ---------------------------------------------------------------------------
// h = LayerNorm(relu(a + b)) * g + bb — one block per row of 256
// ---------------------------------------------------------------------------
__global__ __launch_bounds__(256)
void add_relu_ln(const float* __restrict__ a, const float* __restrict__ b,
                 const float* __restrict__ g, const float* __restrict__ bb,
                 float* __restrict__ o)
{
    const int row = blockIdx.x, t = threadIdx.x;
    const long idx = (long)row * 256 + t;
    float x = fmaxf(a[idx] + b[idx], 0.f);
    float s = x, s2 = x * x;
#pragma unroll
    for (int off = 1; off < 64; off <<= 1) {
        s  += __shfl_xor(s,  off, 64);
        s2 += __shfl_xor(s2, off, 64);
    }
    __shared__ float ws1[4], ws2[4];
    const int wid = t >> 6, lane = t & 63;
    if (lane == 0) { ws1[wid] = s; ws2[wid] = s2; }
    __syncthreads();
    s  = ws1[0] + ws1[1] + ws1[2] + ws1[3];
    s2 = ws2[0] + ws2[1] + ws2[2] + ws2[3];
    const float mu  = s * (1.f / 256.f);
    const float var = s2 * (1.f / 256.f) - mu * mu;
    o[idx] = (x - mu) * rsqrtf(var + 1e-5f) * g[t] + bb[t];
}

// ---------------------------------------------------------------------------
// W2 [256][128] -> transposed + hi/lo bf16 split: w2th/w2tl [128][256]
// ---------------------------------------------------------------------------
__global__ __launch_bounds__(256)
void split_w2t(const float* __restrict__ w2, short* __restrict__ w2th,
               short* __restrict__ w2tl)
{
    int e = blockIdx.x * 256 + threadIdx.x;   // 0..32767
    int k = e >> 7, n = e & 127;
    float x = w2[k * 128 + n];
    unsigned short h = f2bf(x);
    unsigned short lo = f2bf(x - bf2f(h));
    w2th[n * 256 + k] = (short)h;
    w2tl[n * 256 + k] = (short)lo;
}

// ---------------------------------------------------------------------------
// Fused pairwise scorer, MFMA bf16 hi/lo-split (3-pass), fp32 accumulate.
// Block: 128 pairs (2 i x 64 j) x full N=128, one batch.
// 4 waves: 2 (M-halves of 64) x 2 (N-halves of 64).
// K=256 in 8 tiles of 32. P built fp32 in LDS -> split -> swizzled bf16.
// ---------------------------------------------------------------------------
__global__ __launch_bounds__(256)
void pairwise_mfma(const float* __restrict__ hia, const float* __restrict__ hja,
                   const float* __restrict__ bp,
                   const float* __restrict__ c,   // mlp_w1 row 512 [256]
                   const float* __restrict__ b1,  // [256]
                   const short* __restrict__ w2th, const short* __restrict__ w2tl,
                   const float* __restrict__ b2,  // [128]
                   const float* __restrict__ w3,  // [128]
                   const float* __restrict__ b3,  // [1]
                   float* __restrict__ out)
{
    const int b = blockIdx.z, ib0 = blockIdx.y * 2, jb = blockIdx.x;
    const int tid = threadIdx.x;
    const int l = tid & 63, wid = tid >> 6;
    const int wm0 = (wid & 1) * 64, wn0 = (wid >> 1) * 64;

    __shared__ __align__(16) short Ph[128 * 32];   // swizzled: byte ^= (row&7)<<4
    __shared__ __align__(16) short Pl[128 * 32];
    __shared__ __align__(16) float hjs[64][36];
    __shared__ __align__(16) float his[2][36];
    __shared__ __align__(16) float cs[32];
    __shared__ __align__(16) float b1s[32];
    __shared__ float bpv[128];
    __shared__ float red[128][2];

    if (tid < 128) {
        int i = ib0 + (tid >> 6), j = jb * 64 + (tid & 63);
        bpv[tid] = bp[((long)(b * 256 + i)) * 256 + j];
    }

    f32x4 acc[4][4] = {};

    for (int kt = 0; kt < 8; ++kt) {
        const int k0 = kt * 32;
        // ---- stage hj / hi / c / b1 slices (fp32) ----
#pragma unroll
        for (int q = 0; q < 2; ++q) {
            int f = tid * 2 + q;                 // 0..511
            int row = f >> 3, kq = (f & 7) << 2;
            *(float4*)&hjs[row][kq] =
                *(const float4*)&hja[((long)(b * 256 + jb * 64 + row)) * 256 + k0 + kq];
        }
        if (tid < 16) {
            int row = tid >> 3, kq = (tid & 7) << 2;
            *(float4*)&his[row][kq] =
                *(const float4*)&hia[((long)(b * 256 + ib0 + row)) * 256 + k0 + kq];
        } else if (tid < 24) {
            int f = tid - 16;
            *(float4*)&cs[f * 4] = *(const float4*)&c[k0 + f * 4];
        } else if (tid < 32) {
            int f = tid - 24;
            *(float4*)&b1s[f * 4] = *(const float4*)&b1[k0 + f * 4];
        }
        __syncthreads();   // staging visible; prev-tile MFMA done reading P

        // ---- build P tile: 128 pairs x 32 k, split hi/lo, swizzled store ----
        {
            const int p = tid >> 1, kb = (tid & 1) << 4;
            const int ii = p >> 6, jj = p & 63;
            const float bw = bpv[p];
            const int swz = (p & 7) << 4;
            char* phc = (char*)Ph;
            char* plc = (char*)Pl;
#pragma unroll
            for (int q = 0; q < 4; ++q) {
                float4 hv = *(const float4*)&hjs[jj][kb + q * 4];
                float4 iv = *(const float4*)&his[ii][kb + q * 4];
                float4 cv = *(const float4*)&cs[kb + q * 4];
                float4 bv = *(const float4*)&b1s[kb + q * 4];
                float xs[4];
                xs[0] = fmaxf(iv.x + hv.x + bw * cv.x + bv.x, 0.f);
                xs[1] = fmaxf(iv.y + hv.y + bw * cv.y + bv.y, 0.f);
                xs[2] = fmaxf(iv.z + hv.z + bw * cv.z + bv.z, 0.f);
                xs[3] = fmaxf(iv.w + hv.w + bw * cv.w + bv.w, 0.f);
                unsigned hw[4], lw[4];
#pragma unroll
                for (int e = 0; e < 4; ++e) {
                    unsigned short hh = f2bf(xs[e]);
                    unsigned short ll = f2bf(xs[e] - bf2f(hh));
                    hw[e] = hh; lw[e] = ll;
                }
                int base = p * 64 + (kb + q * 4) * 2;      // bytes
                *(unsigned*)(phc + ((base    ) ^ swz)) = hw[0] | (hw[1] << 16);
                *(unsigned*)(phc + ((base + 4) ^ swz)) = hw[2] | (hw[3] << 16);
                *(unsigned*)(plc + ((base    ) ^ swz)) = lw[0] | (lw[1] << 16);
                *(unsigned*)(plc + ((base + 4) ^ swz)) = lw[2] | (lw[3] << 16);
            }
        }
        __syncthreads();   // P tile ready

        // ---- fragments + MFMA (3-pass split) ----
        short8 ah[4], al[4], bh[4], bl[4];
        const int g = l >> 4, ln = l & 15;
#pragma unroll
        for (int mf = 0; mf < 4; ++mf) {
            int row = wm0 + mf * 16 + ln;
            int off = (row * 64 + g * 16) ^ ((row & 7) << 4);
            ah[mf] = *(const short8*)((const char*)Ph + off);
            al[mf] = *(const short8*)((const char*)Pl + off);
        }
#pragma unroll
        for (int nf = 0; nf < 4; ++nf) {
            int col = wn0 + nf * 16 + ln;
            long boff = (long)col * 256 + k0 + g * 8;
            bh[nf] = *(const short8*)(w2th + boff);
            bl[nf] = *(const short8*)(w2tl + boff);
        }
#pragma unroll
        for (int mf = 0; mf < 4; ++mf)
#pragma unroll
            for (int nf = 0; nf < 4; ++nf) {
                acc[mf][nf] = __builtin_amdgcn_mfma_f32_16x16x32_bf16(
                    ah[mf], bh[nf], acc[mf][nf], 0, 0, 0);
                acc[mf][nf] = __builtin_amdgcn_mfma_f32_16x16x32_bf16(
                    ah[mf], bl[nf], acc[mf][nf], 0, 0, 0);
                acc[mf][nf] = __builtin_amdgcn_mfma_f32_16x16x32_bf16(
                    al[mf], bh[nf], acc[mf][nf], 0, 0, 0);
            }
        __syncthreads();   // done reading P before next build
    }

    // ---- epilogue: relu(+b2) dot w3, reduce 16 lanes, cross-wave via LDS ----
    const int g = l >> 4, ln = l & 15;
    float b2v[4], w3v[4];
#pragma unroll
    for (int nf = 0; nf < 4; ++nf) {
        int col = wn0 + nf * 16 + ln;
        b2v[nf] = b2[col];
        w3v[nf] = w3[col];
    }
#pragma unroll
    for (int mf = 0; mf < 4; ++mf) {
#pragma unroll
        for (int r = 0; r < 4; ++r) {
            float s = 0.f;
#pragma unroll
            for (int nf = 0; nf < 4; ++nf)
                s += fmaxf(acc[mf][nf][r] + b2v[nf], 0.f) * w3v[nf];
            s += __shfl_xor(s, 1, 64);
            s += __shfl_xor(s, 2, 64);
            s += __shfl_xor(s, 4, 64);
            s += __shfl_xor(s, 8, 64);
            if (ln == 0)
                red[wm0 + mf * 16 + g * 4 + r][wid >> 1] = s;
        }
    }
    __syncthreads();
    if (tid < 128) {
        int i = ib0 + (tid >> 6), j = jb * 64 + (tid & 63);
        out[((long)(b * 256 + i)) * 256 + j] = red[tid][0] + red[tid][1] + b3[0];
    }
}

// ---------------------------------------------------------------------------
extern "C" void kernel_launch(void* const* d_in, const int* in_sizes, int n_in,
                              void* d_out, int out_size, void* d_ws, size_t ws_size,
                              hipStream_t stream)
{
    const float* emb   = (const float*)d_in[0];
    const float* bp    = (const float*)d_in[1];
    const float* ew1   = (const float*)d_in[3];
    const float* eb1   = (const float*)d_in[4];
    const float* ew2   = (const float*)d_in[5];
    const float* eb2   = (const float*)d_in[6];
    const float* wself = (const float*)d_in[7];
    const float* bself = (const float*)d_in[8];
    const float* wedge = (const float*)d_in[9];
    const float* bedge = (const float*)d_in[10];
    const float* lng   = (const float*)d_in[11];
    const float* lnb   = (const float*)d_in[12];
    const float* mw1   = (const float*)d_in[13];
    const float* mb1   = (const float*)d_in[14];
    const float* mw2   = (const float*)d_in[15];
    const float* mb2   = (const float*)d_in[16];
    const float* mw3   = (const float*)d_in[17];
    const float* mb3   = (const float*)d_in[18];
    float* out = (float*)d_out;

    float* ws = (float*)d_ws;
    float* h1 = ws;               // 1024*512 (dead after enc2; reused for W2T)
    float* h  = h1 + 524288;
    float* sf = h  + 262144;
    float* eg = sf + 262144;
    float* ng = eg + 262144;
    float* hi = ng + 262144;
    float* hj = hi + 262144;      // end: 2,097,152 floats = 8 MB
    short* w2th = (short*)h1;             // 32768 shorts
    short* w2tl = w2th + 32768;           // 32768 shorts (both inside h1 region)

    dim3 blk(256);

    // FeatureEncoder
    gemm32<true ><<<dim3(8, 32, 1), blk, 0, stream>>>(emb, ew1, eb1, h1,
        nullptr, nullptr, nullptr, 1024, 512, 640, 0, 0, 0, 0);
    gemm32<false><<<dim3(4, 32, 1), blk, 0, stream>>>(h1, ew2, eb2, h,
        nullptr, nullptr, nullptr, 1024, 256, 512, 0, 0, 0, 0);

    // W2 transpose+split (h1 is dead from here on)
    split_w2t<<<dim3(128), blk, 0, stream>>>(mw2, w2th, w2tl);

    // GCN layers
    for (int lyr = 0; lyr < 3; ++lyr) {
        gemm32<false><<<dim3(8, 32, 1), blk, 0, stream>>>(h,
            wself + lyr * 65536, bself + lyr * 256, sf,
            wedge + lyr * 65536, bedge + lyr * 256, eg,
            1024, 256, 256, 0, 0, 0, 4);
        gemm32<false><<<dim3(4, 8, 4), blk, 0, stream>>>(bp, eg, nullptr, ng,
            nullptr, nullptr, nullptr, 256, 256, 256, 65536, 65536, 65536, 0);
        add_relu_ln<<<dim3(1024), blk, 0, stream>>>(sf, ng,
            lng + lyr * 256, lnb + lyr * 256, h);
    }

    // hi / hj partial products (dual, shared A)
    gemm32<false><<<dim3(8, 32, 1), blk, 0, stream>>>(h,
        mw1, nullptr, hi, mw1 + 65536, nullptr, hj,
        1024, 256, 256, 0, 0, 0, 4);

    // Fused pairwise MFMA scorer
    pairwise_mfma<<<dim3(4, 128, 4), blk, 0, stream>>>(hi, hj, bp,
        mw1 + 131072, mb1, w2th, w2tl, mb2, mw3, mb3, out);
}